// Round 24
// baseline (80.444 us; speedup 1.0000x reference)
//
#include <hip/hip_runtime.h>
#include <hip/hip_bf16.h>

// Problem constants
#define Bq   4
#define Cc   64
#define Hh   160
#define Ww   160
#define HWp  (Hh * Ww)          // 25600
#define COUTc 64

typedef __attribute__((ext_vector_type(8))) _Float16 f16x8;
typedef __attribute__((ext_vector_type(4))) _Float16 f16x4;
typedef __attribute__((ext_vector_type(4))) float f32x4;
typedef __attribute__((ext_vector_type(2))) float f32x2;
typedef __attribute__((ext_vector_type(4))) int   int4v;

// ws layout (shorts, fp16 bit patterns):
//   wTbF  : 72 frags x 512  (main weights, fragment-major)
//   wToffF: 36 frags x 512  (offset weights, fragment-major)
//   xcl   [b][y][x][c] : 4*25600*64 + 64 (zero pad pixel at end)
#define WTBF_SHORTS   (72 * 512)                    // 36864
#define WTOFFF_SHORTS (36 * 512)                    // 18432
#define XCL_OFS       (WTBF_SHORTS + WTOFFF_SHORTS) // 55296
#define XCL_PIX       ((size_t)Bq * HWp)            // zero pad pixel index
#define XCL_SHORTS    (XCL_PIX * 64 + 64)

// Tile: 64 pixels = 2 rows x 32 cols. Halo: rows y-2..y+3 (6), cols
// x0-2..x0+33 (36), 72 shorts (144 B) per pixel = 31104 B.
// (6 rows cover |dy|<1; dy>=1 (~4-sigma) uses the exact global fallback.)
#define HROWS 6
#define HCOLS 36
#define HPX   72                       // shorts per halo pixel
#define HSTR  (HCOLS * HPX)            // 2592 shorts per halo row

__device__ __forceinline__ short f2h(float f) {
    union { _Float16 h; short s; } v; v.h = (_Float16)f; return v.s;
}
__device__ __forceinline__ unsigned pk2h(float a, float b) {
    union { _Float16 h[2]; unsigned u; } v;
    v.h[0] = (_Float16)a; v.h[1] = (_Float16)b; return v.u;
}
__device__ __forceinline__ f16x8 vsplat(_Float16 v) {
    return (f16x8){v, v, v, v, v, v, v, v};
}

// ---------------------------------------------------------------------------
// Merged prep (unchanged, validated): [0,400) xcl fp16 image; [400,544)
// fragment-major weights; 544 zero pad.
// ---------------------------------------------------------------------------
__global__ __launch_bounds__(256) void prep_all(const float* __restrict__ x,
                                                const float* __restrict__ w,
                                                const float* __restrict__ w_off,
                                                short* __restrict__ ws) {
    int blk = blockIdx.x;
    int tid = threadIdx.x;
    if (blk < 400) {
        int g = blk * 256 + tid;             // pixel id
        int b = g / HWp, p = g - b * HWp;
        const float* xp = x + (size_t)b * Cc * HWp + p;
        short* op = ws + XCL_OFS + (size_t)g * 64;
#pragma unroll
        for (int cg = 0; cg < 8; ++cg) {
            unsigned d[4];
#pragma unroll
            for (int dj = 0; dj < 4; ++dj) {
                float f0 = xp[(size_t)(cg * 8 + 2 * dj) * HWp];
                float f1 = xp[(size_t)(cg * 8 + 2 * dj + 1) * HWp];
                d[dj] = pk2h(f0, f1);
            }
            *(int4v*)(op + cg * 8) = *(int4v*)d;
        }
    } else if (blk < 544) {
        int i = (blk - 400) * 256 + tid;
        if (i < WTBF_SHORTS) {
            int fidx = i >> 9, r = i & 511;
            int l = r >> 3, j = r & 7;
            int cg = fidx & 3, th = fidx >> 2;
            int tap = th >> 1, h = th & 1;
            int o = cg * 16 + (l & 15);
            int c = h * 32 + ((l >> 4) << 3) + j;
            ws[i] = f2h(w[o * 576 + c * 9 + tap]);
        }
        if (i < WTOFFF_SHORTS) {
            int fidx = i >> 9, r = i & 511;
            int l = r >> 3, j = r & 7;
            int g = fidx & 1, th = fidx >> 1;
            int tap = th >> 1, h = th & 1;
            int oc = g * 16 + (l & 15);
            int c = h * 32 + ((l >> 4) << 3) + j;
            float v = (oc < 18) ? w_off[oc * 576 + c * 9 + tap] : 0.f;
            ws[WTBF_SHORTS + i] = f2h(v);
        }
    } else {
        if (tid < 8)
            *(int4v*)((char*)(ws + XCL_OFS) + XCL_PIX * 128 + tid * 16) =
                (int4v){0, 0, 0, 0};
    }
}

// ---------------------------------------------------------------------------
// Fused kernel: R20/R23 geometry (64-px tile, 2 rows x 32 cols, wave = 16 px
// x 64 oc) with LDS squeezed to 36.2 KB -> 4 blocks/CU at (256,4):
//   - HROWS 6 (was 7)
//   - tapT removed: per-lane register tables (hoT/wgT), phase 2 deleted.
// ---------------------------------------------------------------------------
__global__ __launch_bounds__(256, 4) void fused_cl(const short* __restrict__ ws,
                                                   const float* __restrict__ b_off,
                                                   const float* __restrict__ bias,
                                                   float* __restrict__ out) {
    __shared__ short halo_s[HROWS * HCOLS * HPX];  // 31104 B
    __shared__ float offbuf[64][20];               // 5120 B

    int tid = threadIdx.x;
    int wid = tid >> 6;
    int l   = tid & 63;
    int lr  = l & 15;
    int lg  = l >> 4;

    // XCD-aware swizzle: nwg = 1600, 1600 % 8 == 0 -> bijective
    int bid = blockIdx.x;
    int g_blk = (bid & 7) * 200 + (bid >> 3);

    // 2D tiling: 400 tiles/image = 80 tile-rows x 5 tile-cols
    int b  = g_blk / 400;
    int r  = g_blk - b * 400;
    int ty2 = r / 5;
    int tx2 = r - ty2 * 5;
    int y  = ty2 * 2;             // rows y, y+1
    int x0 = tx2 * 32;            // cols x0 .. x0+31

    const short* wTbF   = ws;
    const short* wToffF = ws + WTBF_SHORTS;
    const char*  xclb   = (const char*)(ws + XCL_OFS) + (size_t)b * HWp * 128;

    // ---------------- Phase 0: cooperative halo fill (coalesced) ----------
    for (int i = tid; i < HROWS * HCOLS * 8; i += 256) {
        int pl = i >> 3, cg2 = i & 7;
        int hy = pl / HCOLS, hx = pl - hy * HCOLS;
        int gy = y - 2 + hy, gx = x0 - 2 + hx;
        int4v v;
        if (gy >= 0 && gy < Hh && gx >= 0 && gx < Ww)
            v = *(const int4v*)(xclb + (size_t)(gy * Ww + gx) * 128 + cg2 * 16);
        else
            v = (int4v){0, 0, 0, 0};
        *(int4v*)(halo_s + pl * HPX + cg2 * 8) = v;
    }
    __syncthreads();

    // ---------------- Phase 1: offset GEMM, per wave 16 px x 32 oc --------
    {
        int rowoff = wid >> 1;                    // 0 or 1 (tile row)
        int colw   = (wid & 1) * 16 + lr;         // col within tile 0..31
        int hxb    = colw + 1;                    // hx of tap tx=0
        int hoffA[9];
#pragma unroll
        for (int t = 0; t < 9; ++t) {
            int ty = t / 3, tx = t - ty * 3;
            hoffA[t] = (rowoff + ty + 1) * HSTR + (hxb + tx) * HPX + lg * 8;
        }
        const short* wofr = wToffF + l * 8;
        f32x4 accO0 = {0.f, 0.f, 0.f, 0.f};      // oc 0..15
        f32x4 accO1 = {0.f, 0.f, 0.f, 0.f};      // oc 16..31 (18 used)
        f16x8 sB0[4], sB1[4];
#pragma unroll
        for (int u = 0; u < 4; ++u) {
            sB0[u] = *(const f16x8*)(wofr + u * 1024);
            sB1[u] = *(const f16x8*)(wofr + u * 1024 + 512);
        }
        f16x8 sa2[2];
        sa2[0] = *(const f16x8*)(halo_s + hoffA[0]);
#pragma unroll
        for (int u = 0; u < 18; ++u) {
            const int s4 = u & 3;
            if (u + 1 < 18) {
                const int t2 = (u + 1) >> 1, h2 = (u + 1) & 1;
                sa2[(u + 1) & 1] = *(const f16x8*)(halo_s + hoffA[t2] + h2 * 32);
            }
            accO0 = __builtin_amdgcn_mfma_f32_16x16x32_f16(sa2[u & 1], sB0[s4], accO0, 0, 0, 0);
            accO1 = __builtin_amdgcn_mfma_f32_16x16x32_f16(sa2[u & 1], sB1[s4], accO1, 0, 0, 0);
            if (u + 4 < 18) {
                sB0[s4] = *(const f16x8*)(wofr + (u + 4) * 1024);
                sB1[s4] = *(const f16x8*)(wofr + (u + 4) * 1024 + 512);
            }
            __builtin_amdgcn_sched_barrier(0);
        }
        // C: col=lr (oc), row=lg*4+j (pixel within wave's 16)
        float bv0 = b_off[lr];
#pragma unroll
        for (int j = 0; j < 4; ++j)
            offbuf[wid * 16 + lg * 4 + j][lr] = accO0[j] + bv0;
        if (lr < 2) {
            float bv1 = b_off[16 + lr];
#pragma unroll
            for (int j = 0; j < 4; ++j)
                offbuf[wid * 16 + lg * 4 + j][16 + lr] = accO1[j] + bv1;
        }
    }
    __syncthreads();

    // ---------------- Phase 3 prologue: per-lane register tables ----------
    int px3 = wid * 16 + lr;                      // this lane's pixel 0..63
    int prow = px3 >> 5, pcol = px3 & 31;
    int   hoT[9];
    f16x4 wgT[9];
#pragma unroll
    for (int t = 0; t < 9; ++t) {
        int ty = t / 3, tx = t - ty * 3;
        f32x2 d2 = *(const f32x2*)&offbuf[px3][2 * t];
        float py  = (float)(y + prow - 1 + ty) + d2[0];
        float pxf = (float)(x0 + pcol - 1 + tx) + d2[1];
        float fy = floorf(py), fx = floorf(pxf);
        float ly = py - fy, lx = pxf - fx;
        int iy0 = (int)fy, ix0 = (int)fx;
        int iy1 = iy0 + 1, ix1 = ix0 + 1;
        bool vy0 = (iy0 >= 0) && (iy0 < Hh);
        bool vy1 = (iy1 >= 0) && (iy1 < Hh);
        bool vx0 = (ix0 >= 0) && (ix0 < Ww);
        bool vx1 = (ix1 >= 0) && (ix1 < Ww);
        float w00 = (vy0 && vx0) ? (1.f - ly) * (1.f - lx) : 0.f;
        float w01 = (vy0 && vx1) ? (1.f - ly) * lx         : 0.f;
        float w10 = (vy1 && vx0) ? ly * (1.f - lx)         : 0.f;
        float w11 = (vy1 && vx1) ? ly * lx                 : 0.f;
        int hy = iy0 - (y - 2);
        int hx = ix0 - (x0 - 2);
        bool inH = (hy >= 0) && (hy <= HROWS - 2) && (hx >= 0) && (hx <= HCOLS - 2);
        hoT[t] = inH ? (hy * HSTR + hx * HPX) : -1;
        wgT[t] = (f16x4){(_Float16)w00, (_Float16)w01,
                         (_Float16)w10, (_Float16)w11};
    }

    // ---------------- Phase 3: main GEMM, wave = 16 px x 64 oc ------------
    f32x4 acc[4];
#pragma unroll
    for (int cg = 0; cg < 4; ++cg) acc[cg] = (f32x4){0.f, 0.f, 0.f, 0.f};
    const short* wfb = wTbF + l * 8;

    f16x8 sBc[2][4];
#pragma unroll
    for (int cg = 0; cg < 4; ++cg) {
        sBc[0][cg] = *(const f16x8*)(wfb + (0 * 4 + cg) * 512);
        sBc[1][cg] = *(const f16x8*)(wfb + (1 * 4 + cg) * 512);
    }

    f16x8 cst[2][8];       // [slot][h*4 + corner]
    {
        const short* q = halo_s + max(hoT[0], 0) + lg * 8;
#pragma unroll
        for (int h = 0; h < 2; ++h) {
            const short* qh = q + h * 32;
            cst[0][h * 4 + 0] = *(const f16x8*)(qh);
            cst[0][h * 4 + 1] = *(const f16x8*)(qh + HPX);
            cst[0][h * 4 + 2] = *(const f16x8*)(qh + HSTR);
            cst[0][h * 4 + 3] = *(const f16x8*)(qh + HSTR + HPX);
        }
    }

#pragma unroll
    for (int t = 0; t < 9; ++t) {
        const int cur = t & 1, nx = cur ^ 1;
        const int ho = hoT[t];
        f16x4 wg = wgT[t];

        if (t < 8) {
            const short* q = halo_s + max(hoT[t + 1], 0) + lg * 8;
#pragma unroll
            for (int h = 0; h < 2; ++h) {
                const short* qh = q + h * 32;
                cst[nx][h * 4 + 0] = *(const f16x8*)(qh);
                cst[nx][h * 4 + 1] = *(const f16x8*)(qh + HPX);
                cst[nx][h * 4 + 2] = *(const f16x8*)(qh + HSTR);
                cst[nx][h * 4 + 3] = *(const f16x8*)(qh + HSTR + HPX);
            }
        }
        __builtin_amdgcn_sched_barrier(0);

#pragma unroll
        for (int h = 0; h < 2; ++h) {
            const int u = 2 * t + h, s = u & 1;
            f16x8 a = cst[cur][h * 4 + 0] * vsplat(wg[0])
                    + cst[cur][h * 4 + 1] * vsplat(wg[1])
                    + cst[cur][h * 4 + 2] * vsplat(wg[2])
                    + cst[cur][h * 4 + 3] * vsplat(wg[3]);
            if (ho < 0) {   // rare out-of-halo fallback (|offset| >= ~1)
                int ty_ = t / 3, tx_ = t - ty_ * 3;
                f32x2 d2 = *(const f32x2*)&offbuf[px3][2 * t];
                float py  = (float)(y + prow - 1 + ty_) + d2[0];
                float pxf = (float)(x0 + pcol - 1 + tx_) + d2[1];
                int iy0 = (int)floorf(py), ix0 = (int)floorf(pxf);
                int cy0 = min(max(iy0, 0), Hh - 1), cy1 = min(max(iy0 + 1, 0), Hh - 1);
                int cx0 = min(max(ix0, 0), Ww - 1), cx1 = min(max(ix0 + 1, 0), Ww - 1);
                int cbh = h * 64 + lg * 16;
                f16x8 g00 = *(const f16x8*)(xclb + (size_t)(cy0 * Ww + cx0) * 128 + cbh);
                f16x8 g01 = *(const f16x8*)(xclb + (size_t)(cy0 * Ww + cx1) * 128 + cbh);
                f16x8 g10 = *(const f16x8*)(xclb + (size_t)(cy1 * Ww + cx0) * 128 + cbh);
                f16x8 g11 = *(const f16x8*)(xclb + (size_t)(cy1 * Ww + cx1) * 128 + cbh);
                a = g00 * vsplat(wg[0]) + g01 * vsplat(wg[1])
                  + g10 * vsplat(wg[2]) + g11 * vsplat(wg[3]);
            }
            acc[0] = __builtin_amdgcn_mfma_f32_16x16x32_f16(a, sBc[s][0], acc[0], 0, 0, 0);
            acc[1] = __builtin_amdgcn_mfma_f32_16x16x32_f16(a, sBc[s][1], acc[1], 0, 0, 0);
            acc[2] = __builtin_amdgcn_mfma_f32_16x16x32_f16(a, sBc[s][2], acc[2], 0, 0, 0);
            acc[3] = __builtin_amdgcn_mfma_f32_16x16x32_f16(a, sBc[s][3], acc[3], 0, 0, 0);
            if (u + 2 < 18) {
#pragma unroll
                for (int cg = 0; cg < 4; ++cg)
                    sBc[s][cg] = *(const f16x8*)(wfb + ((u + 2) * 4 + cg) * 512);
            }
        }
        __builtin_amdgcn_sched_barrier(0);
    }

    // ---------------- Epilogue: 16 px x 64 oc per wave --------------------
    float* obase = out + (size_t)b * COUTc * HWp + y * Ww + x0;
#pragma unroll
    for (int cg = 0; cg < 4; ++cg) {
        int o = cg * 16 + lr;
        float bv = bias[o];
#pragma unroll
        for (int j = 0; j < 4; ++j) {
            int px = wid * 16 + lg * 4 + j;
            int prw = px >> 5, pcl = px & 31;
            obase[(size_t)o * HWp + prw * Ww + pcl] = acc[cg][j] + bv;
        }
    }
}

// ---------------------------------------------------------------------------
extern "C" void kernel_launch(void* const* d_in, const int* in_sizes, int n_in,
                              void* d_out, int out_size, void* d_ws, size_t ws_size,
                              hipStream_t stream) {
    const float* x      = (const float*)d_in[0];
    const float* w_off  = (const float*)d_in[1];
    const float* b_off  = (const float*)d_in[2];
    const float* weight = (const float*)d_in[3];
    const float* bias   = (const float*)d_in[4];
    float* outp = (float*)d_out;
    short* ws   = (short*)d_ws;

    // 400 blocks xcl + 144 blocks weights + 1 block zero pad
    prep_all<<<545, 256, 0, stream>>>(x, weight, w_off, ws);

    int nblocks = (Bq * HWp) / 64;   // 1600 workgroups, 64 pixels each
    fused_cl<<<nblocks, 256, 0, stream>>>(ws, b_off, bias, outp);
}

// Round 25
// 49.633 us; speedup vs baseline: 1.6208x; 1.6208x over previous
//
#include <hip/hip_runtime.h>
#include <hip/hip_bf16.h>

// Problem constants
#define Bq   4
#define Cc   64
#define Hh   160
#define Ww   160
#define HWp  (Hh * Ww)          // 25600
#define COUTc 64

typedef __attribute__((ext_vector_type(8))) _Float16 f16x8;
typedef __attribute__((ext_vector_type(4))) _Float16 f16x4;
typedef __attribute__((ext_vector_type(4))) float f32x4;
typedef __attribute__((ext_vector_type(2))) float f32x2;
typedef __attribute__((ext_vector_type(4))) int   int4v;

// ws layout (shorts, fp16 bit patterns):
//   wTbF  : 72 frags x 512  (main weights, fragment-major)
//   wToffF: 36 frags x 512  (offset weights, fragment-major)
//   xcl   [b][y][x][c] : 4*25600*64 + 64 (zero pad pixel at end)
#define WTBF_SHORTS   (72 * 512)                    // 36864
#define WTOFFF_SHORTS (36 * 512)                    // 18432
#define XCL_OFS       (WTBF_SHORTS + WTOFFF_SHORTS) // 55296
#define XCL_PIX       ((size_t)Bq * HWp)            // zero pad pixel index
#define XCL_SHORTS    (XCL_PIX * 64 + 64)

// Tile: 64 pixels = 2 rows x 32 cols. Halo: rows y-2..y+4 (7), cols
// x0-2..x0+33 (36), 72 shorts (144 B) per pixel.
#define HROWS 7
#define HCOLS 36
#define HPX   72                       // shorts per halo pixel
#define HSTR  (HCOLS * HPX)            // 2592 shorts per halo row

__device__ __forceinline__ short f2h(float f) {
    union { _Float16 h; short s; } v; v.h = (_Float16)f; return v.s;
}
__device__ __forceinline__ unsigned pk2h(float a, float b) {
    union { _Float16 h[2]; unsigned u; } v;
    v.h[0] = (_Float16)a; v.h[1] = (_Float16)b; return v.u;
}
__device__ __forceinline__ f16x8 vsplat(_Float16 v) {
    return (f16x8){v, v, v, v, v, v, v, v};
}

// ---------------------------------------------------------------------------
// Merged prep (unchanged, validated): [0,400) xcl fp16 image; [400,544)
// fragment-major weights; 544 zero pad.
// ---------------------------------------------------------------------------
__global__ __launch_bounds__(256) void prep_all(const float* __restrict__ x,
                                                const float* __restrict__ w,
                                                const float* __restrict__ w_off,
                                                short* __restrict__ ws) {
    int blk = blockIdx.x;
    int tid = threadIdx.x;
    if (blk < 400) {
        int g = blk * 256 + tid;             // pixel id
        int b = g / HWp, p = g - b * HWp;
        const float* xp = x + (size_t)b * Cc * HWp + p;
        short* op = ws + XCL_OFS + (size_t)g * 64;
#pragma unroll
        for (int cg = 0; cg < 8; ++cg) {
            unsigned d[4];
#pragma unroll
            for (int dj = 0; dj < 4; ++dj) {
                float f0 = xp[(size_t)(cg * 8 + 2 * dj) * HWp];
                float f1 = xp[(size_t)(cg * 8 + 2 * dj + 1) * HWp];
                d[dj] = pk2h(f0, f1);
            }
            *(int4v*)(op + cg * 8) = *(int4v*)d;
        }
    } else if (blk < 544) {
        int i = (blk - 400) * 256 + tid;
        if (i < WTBF_SHORTS) {
            int fidx = i >> 9, r = i & 511;
            int l = r >> 3, j = r & 7;
            int cg = fidx & 3, th = fidx >> 2;
            int tap = th >> 1, h = th & 1;
            int o = cg * 16 + (l & 15);
            int c = h * 32 + ((l >> 4) << 3) + j;
            ws[i] = f2h(w[o * 576 + c * 9 + tap]);
        }
        if (i < WTOFFF_SHORTS) {
            int fidx = i >> 9, r = i & 511;
            int l = r >> 3, j = r & 7;
            int g = fidx & 1, th = fidx >> 1;
            int tap = th >> 1, h = th & 1;
            int oc = g * 16 + (l & 15);
            int c = h * 32 + ((l >> 4) << 3) + j;
            float v = (oc < 18) ? w_off[oc * 576 + c * 9 + tap] : 0.f;
            ws[WTBF_SHORTS + i] = f2h(v);
        }
    } else {
        if (tid < 8)
            *(int4v*)((char*)(ws + XCL_OFS) + XCL_PIX * 128 + tid * 16) =
                (int4v){0, 0, 0, 0};
    }
}

// ---------------------------------------------------------------------------
// Fused kernel (R20/R23 champion): 64-pixel tile (2 rows x 32 cols),
// 1 wave = 16 px x 64 outch; LDS halo; packed tables; pipelined phase 3.
// __launch_bounds__(256,3): VGPR 80, NO SPILL — higher-occupancy variants
// spilled (WRITE_SIZE 139-145 MB scratch traffic, R21/R22/R24).
// ---------------------------------------------------------------------------
__global__ __launch_bounds__(256, 3) void fused_cl(const short* __restrict__ ws,
                                                   const float* __restrict__ b_off,
                                                   const float* __restrict__ bias,
                                                   float* __restrict__ out) {
    __shared__ short halo_s[HROWS * HCOLS * HPX];  // 36288 B
    __shared__ float offbuf[64][20];               // 5120 B
    __shared__ int4v tapT[64][9];                  // 9216 B {ho, iy0|ix0<<16, wg}

    int tid = threadIdx.x;
    int wid = tid >> 6;
    int l   = tid & 63;
    int lr  = l & 15;
    int lg  = l >> 4;

    // XCD-aware swizzle: nwg = 1600, 1600 % 8 == 0 -> bijective
    int bid = blockIdx.x;
    int g_blk = (bid & 7) * 200 + (bid >> 3);

    // 2D tiling: 400 tiles/image = 80 tile-rows x 5 tile-cols
    int b  = g_blk / 400;
    int r  = g_blk - b * 400;
    int ty2 = r / 5;
    int tx2 = r - ty2 * 5;
    int y  = ty2 * 2;             // rows y, y+1
    int x0 = tx2 * 32;            // cols x0 .. x0+31

    const short* wTbF   = ws;
    const short* wToffF = ws + WTBF_SHORTS;
    const char*  xclb   = (const char*)(ws + XCL_OFS) + (size_t)b * HWp * 128;

    // ---------------- Phase 0: cooperative halo fill (coalesced) ----------
    for (int i = tid; i < HROWS * HCOLS * 8; i += 256) {
        int pl = i >> 3, cg2 = i & 7;
        int hy = pl / HCOLS, hx = pl - hy * HCOLS;
        int gy = y - 2 + hy, gx = x0 - 2 + hx;
        int4v v;
        if (gy >= 0 && gy < Hh && gx >= 0 && gx < Ww)
            v = *(const int4v*)(xclb + (size_t)(gy * Ww + gx) * 128 + cg2 * 16);
        else
            v = (int4v){0, 0, 0, 0};
        *(int4v*)(halo_s + pl * HPX + cg2 * 8) = v;
    }
    __syncthreads();

    // ---------------- Phase 1: offset GEMM, per wave 16 px x 32 oc --------
    {
        int rowoff = wid >> 1;                    // 0 or 1 (tile row)
        int colw   = (wid & 1) * 16 + lr;         // col within tile 0..31
        int hxb    = colw + 1;                    // hx of tap tx=0
        int hoffA[9];
#pragma unroll
        for (int t = 0; t < 9; ++t) {
            int ty = t / 3, tx = t - ty * 3;
            hoffA[t] = (rowoff + ty + 1) * HSTR + (hxb + tx) * HPX + lg * 8;
        }
        const short* wofr = wToffF + l * 8;
        f32x4 accO0 = {0.f, 0.f, 0.f, 0.f};      // oc 0..15
        f32x4 accO1 = {0.f, 0.f, 0.f, 0.f};      // oc 16..31 (18 used)
        f16x8 sB0[4], sB1[4];
#pragma unroll
        for (int u = 0; u < 4; ++u) {
            sB0[u] = *(const f16x8*)(wofr + u * 1024);
            sB1[u] = *(const f16x8*)(wofr + u * 1024 + 512);
        }
        f16x8 sa2[2];
        sa2[0] = *(const f16x8*)(halo_s + hoffA[0]);
#pragma unroll
        for (int u = 0; u < 18; ++u) {
            const int s4 = u & 3;
            if (u + 1 < 18) {
                const int t2 = (u + 1) >> 1, h2 = (u + 1) & 1;
                sa2[(u + 1) & 1] = *(const f16x8*)(halo_s + hoffA[t2] + h2 * 32);
            }
            accO0 = __builtin_amdgcn_mfma_f32_16x16x32_f16(sa2[u & 1], sB0[s4], accO0, 0, 0, 0);
            accO1 = __builtin_amdgcn_mfma_f32_16x16x32_f16(sa2[u & 1], sB1[s4], accO1, 0, 0, 0);
            if (u + 4 < 18) {
                sB0[s4] = *(const f16x8*)(wofr + (u + 4) * 1024);
                sB1[s4] = *(const f16x8*)(wofr + (u + 4) * 1024 + 512);
            }
            __builtin_amdgcn_sched_barrier(0);
        }
        // C: col=lr (oc), row=lg*4+j (pixel within wave's 16)
        float bv0 = b_off[lr];
#pragma unroll
        for (int j = 0; j < 4; ++j)
            offbuf[wid * 16 + lg * 4 + j][lr] = accO0[j] + bv0;
        if (lr < 2) {
            float bv1 = b_off[16 + lr];
#pragma unroll
            for (int j = 0; j < 4; ++j)
                offbuf[wid * 16 + lg * 4 + j][16 + lr] = accO1[j] + bv1;
        }
    }
    __syncthreads();

    // ---------------- Phase 2: packed tables (64 px x 9 taps) -------------
    for (int i = tid; i < 576; i += 256) {
        int px = i / 9, tap = i - px * 9;
        int prow = px >> 5, pcol = px & 31;
        int ty = tap / 3, tx = tap - ty * 3;
        f32x2 d2 = *(const f32x2*)&offbuf[px][2 * tap];
        float py  = (float)(y + prow - 1 + ty) + d2[0];
        float pxf = (float)(x0 + pcol - 1 + tx) + d2[1];
        float fy = floorf(py), fx = floorf(pxf);
        float ly = py - fy, lx = pxf - fx;
        int iy0 = (int)fy, ix0 = (int)fx;
        int iy1 = iy0 + 1, ix1 = ix0 + 1;
        bool vy0 = (iy0 >= 0) && (iy0 < Hh);
        bool vy1 = (iy1 >= 0) && (iy1 < Hh);
        bool vx0 = (ix0 >= 0) && (ix0 < Ww);
        bool vx1 = (ix1 >= 0) && (ix1 < Ww);
        float w00 = (vy0 && vx0) ? (1.f - ly) * (1.f - lx) : 0.f;
        float w01 = (vy0 && vx1) ? (1.f - ly) * lx         : 0.f;
        float w10 = (vy1 && vx0) ? ly * (1.f - lx)         : 0.f;
        float w11 = (vy1 && vx1) ? ly * lx                 : 0.f;
        int hy = iy0 - (y - 2);
        int hx = ix0 - (x0 - 2);
        bool inH = (hy >= 0) && (hy <= HROWS - 2) && (hx >= 0) && (hx <= HCOLS - 2);
        union { f16x4 h4; int iw[2]; } wu;
        wu.h4 = (f16x4){(_Float16)w00, (_Float16)w01,
                        (_Float16)w10, (_Float16)w11};
        int4v tv;
        tv[0] = inH ? (hy * HSTR + hx * HPX) : -1;
        tv[1] = (iy0 & 0xffff) | (ix0 << 16);
        tv[2] = wu.iw[0];
        tv[3] = wu.iw[1];
        tapT[px][tap] = tv;
    }
    __syncthreads();

    // ---------------- Phase 3: main GEMM, wave = 16 px x 64 oc ------------
    f32x4 acc[4];
#pragma unroll
    for (int cg = 0; cg < 4; ++cg) acc[cg] = (f32x4){0.f, 0.f, 0.f, 0.f};
    int px3 = wid * 16 + lr;                      // pixel 0..63
    const short* wfb = wTbF + l * 8;

    f16x8 sBc[2][4];
#pragma unroll
    for (int cg = 0; cg < 4; ++cg) {
        sBc[0][cg] = *(const f16x8*)(wfb + (0 * 4 + cg) * 512);
        sBc[1][cg] = *(const f16x8*)(wfb + (1 * 4 + cg) * 512);
    }

    int4v tp[2];
    tp[0] = tapT[px3][0];
    tp[1] = tapT[px3][1];

    f16x8 cst[2][8];       // [slot][h*4 + corner]
    {
        const short* q = halo_s + max(tp[0][0], 0) + lg * 8;
#pragma unroll
        for (int h = 0; h < 2; ++h) {
            const short* qh = q + h * 32;
            cst[0][h * 4 + 0] = *(const f16x8*)(qh);
            cst[0][h * 4 + 1] = *(const f16x8*)(qh + HPX);
            cst[0][h * 4 + 2] = *(const f16x8*)(qh + HSTR);
            cst[0][h * 4 + 3] = *(const f16x8*)(qh + HSTR + HPX);
        }
    }

#pragma unroll
    for (int t = 0; t < 9; ++t) {
        const int cur = t & 1, nx = cur ^ 1;

        const int ho = tp[cur][0];
        const int fb = tp[cur][1];
        union { int iw[2]; f16x4 h4; } wu;
        wu.iw[0] = tp[cur][2];
        wu.iw[1] = tp[cur][3];
        f16x4 wg = wu.h4;

        if (t + 2 < 9)
            tp[cur] = tapT[px3][t + 2];

        if (t < 8) {
            const short* q = halo_s + max(tp[nx][0], 0) + lg * 8;
#pragma unroll
            for (int h = 0; h < 2; ++h) {
                const short* qh = q + h * 32;
                cst[nx][h * 4 + 0] = *(const f16x8*)(qh);
                cst[nx][h * 4 + 1] = *(const f16x8*)(qh + HPX);
                cst[nx][h * 4 + 2] = *(const f16x8*)(qh + HSTR);
                cst[nx][h * 4 + 3] = *(const f16x8*)(qh + HSTR + HPX);
            }
        }
        __builtin_amdgcn_sched_barrier(0);

#pragma unroll
        for (int h = 0; h < 2; ++h) {
            const int u = 2 * t + h, s = u & 1;
            f16x8 a = cst[cur][h * 4 + 0] * vsplat(wg[0])
                    + cst[cur][h * 4 + 1] * vsplat(wg[1])
                    + cst[cur][h * 4 + 2] * vsplat(wg[2])
                    + cst[cur][h * 4 + 3] * vsplat(wg[3]);
            if (ho < 0) {   // rare out-of-halo fallback (|offset| > ~1)
                int iy0 = (int)(short)(fb & 0xffff);
                int ix0 = fb >> 16;
                int cy0 = min(max(iy0, 0), Hh - 1), cy1 = min(max(iy0 + 1, 0), Hh - 1);
                int cx0 = min(max(ix0, 0), Ww - 1), cx1 = min(max(ix0 + 1, 0), Ww - 1);
                int cbh = h * 64 + lg * 16;
                f16x8 g00 = *(const f16x8*)(xclb + (size_t)(cy0 * Ww + cx0) * 128 + cbh);
                f16x8 g01 = *(const f16x8*)(xclb + (size_t)(cy0 * Ww + cx1) * 128 + cbh);
                f16x8 g10 = *(const f16x8*)(xclb + (size_t)(cy1 * Ww + cx0) * 128 + cbh);
                f16x8 g11 = *(const f16x8*)(xclb + (size_t)(cy1 * Ww + cx1) * 128 + cbh);
                a = g00 * vsplat(wg[0]) + g01 * vsplat(wg[1])
                  + g10 * vsplat(wg[2]) + g11 * vsplat(wg[3]);
            }
            acc[0] = __builtin_amdgcn_mfma_f32_16x16x32_f16(a, sBc[s][0], acc[0], 0, 0, 0);
            acc[1] = __builtin_amdgcn_mfma_f32_16x16x32_f16(a, sBc[s][1], acc[1], 0, 0, 0);
            acc[2] = __builtin_amdgcn_mfma_f32_16x16x32_f16(a, sBc[s][2], acc[2], 0, 0, 0);
            acc[3] = __builtin_amdgcn_mfma_f32_16x16x32_f16(a, sBc[s][3], acc[3], 0, 0, 0);
            if (u + 2 < 18) {
#pragma unroll
                for (int cg = 0; cg < 4; ++cg)
                    sBc[s][cg] = *(const f16x8*)(wfb + ((u + 2) * 4 + cg) * 512);
            }
        }
        __builtin_amdgcn_sched_barrier(0);
    }

    // ---------------- Epilogue: 16 px x 64 oc per wave --------------------
    float* obase = out + (size_t)b * COUTc * HWp + y * Ww + x0;
#pragma unroll
    for (int cg = 0; cg < 4; ++cg) {
        int o = cg * 16 + lr;
        float bv = bias[o];
#pragma unroll
        for (int j = 0; j < 4; ++j) {
            int px = wid * 16 + lg * 4 + j;
            int prow = px >> 5, pcol = px & 31;
            obase[(size_t)o * HWp + prow * Ww + pcol] = acc[cg][j] + bv;
        }
    }
}

// ---------------------------------------------------------------------------
extern "C" void kernel_launch(void* const* d_in, const int* in_sizes, int n_in,
                              void* d_out, int out_size, void* d_ws, size_t ws_size,
                              hipStream_t stream) {
    const float* x      = (const float*)d_in[0];
    const float* w_off  = (const float*)d_in[1];
    const float* b_off  = (const float*)d_in[2];
    const float* weight = (const float*)d_in[3];
    const float* bias   = (const float*)d_in[4];
    float* outp = (float*)d_out;
    short* ws   = (short*)d_ws;

    // 400 blocks xcl + 144 blocks weights + 1 block zero pad
    prep_all<<<545, 256, 0, stream>>>(x, weight, w_off, ws);

    int nblocks = (Bq * HWp) / 64;   // 1600 workgroups, 64 pixels each
    fused_cl<<<nblocks, 256, 0, stream>>>(ws, b_off, bias, outp);
}